// Round 16
// baseline (35.494 us; speedup 1.0000x reference)
//
#include <hip/hip_runtime.h>
#include <hip/hip_bf16.h>

#define K_DIM 8192
#define L_DIM 1024
#define C2 240
#define MSTRIDE 256                 // padded m stride in partials
#define BM 128
#define BN 128
#define BK 64
#define KSPLIT 16
#define KCHUNK 512                  // K_DIM / KSPLIT
#define NSTEP 8                     // KCHUNK / BK
#define PART_KC (L_DIM * MSTRIDE)   // 262144 bf16 elems per k-chunk
#define PART_BYTES ((size_t)KSPLIT * PART_KC * 2)   // 8,388,608
#define WSWZ_CHUNKS (2 * 16 * 8 * 1024)             // mtile*kc*step*1024
#define WSWZ_BYTES ((size_t)WSWZ_CHUNKS * 16)       // 4 MB
#define TOT_F4 (10000 * 256)

typedef __attribute__((ext_vector_type(4))) float f32x4;
typedef __attribute__((ext_vector_type(2))) float f32x2;
typedef __attribute__((ext_vector_type(8))) short bf16x8;
typedef __attribute__((ext_vector_type(4))) short bf16x4;

__device__ __forceinline__ unsigned short f2bf(float f) {
  return __builtin_bit_cast(unsigned short, __float2bfloat16(f));
}
__device__ __forceinline__ float bf2f(unsigned short h) {
  unsigned u = ((unsigned)h) << 16;
  return __builtin_bit_cast(float, u);
}

// Async global->LDS, 16B per lane: LDS dest = wave-uniform base + lane*16,
// global src = per-lane address. Completion tracked by vmcnt; __syncthreads
// (full drain) guarantees arrival before the consuming MFMA phase.
__device__ __forceinline__ void gload16(const unsigned short* g,
                                        unsigned short* lds) {
  typedef __attribute__((address_space(3))) unsigned int lds_u32;
  typedef __attribute__((address_space(1))) const unsigned int glb_u32;
  __builtin_amdgcn_global_load_lds((glb_u32*)g, (lds_u32*)lds, 16, 0, 0);
}

// -------- Stage 0: one-time W convert: fp32 -> bf16, pad m to 256, --------
// -------- PRE-SWIZZLED into the exact per-(mtile,kc,step) LDS image --------
// Chunk (16B, 8 bf16) at slab=((mtile*16+kc)*8+s), Q=(m_local*8+c') holds
// source k-octet c = c' ^ (m_local&7) of row m — the same XOR the GEMM read
// side uses, so gload_lds can write LDS strictly linearly (rule: source
// permutation == read permutation).
__global__ __launch_bounds__(256) void k_wconv(
    const float* __restrict__ W, unsigned short* __restrict__ Wswz)
{
  const int g  = blockIdx.x * 256 + threadIdx.x;   // chunk id 0..262143
  const int Q  = g & 1023;
  const int sl = g >> 10;
  const int ml = Q >> 3;
  const int cp = Q & 7;
  const int s  = sl & 7;
  const int kc = (sl >> 3) & 15;
  const int mt = sl >> 7;
  const int mg = mt * BM + ml;
  const int k  = kc * KCHUNK + s * BK + (cp ^ (ml & 7)) * 8;

  bf16x8 v = (bf16x8){0, 0, 0, 0, 0, 0, 0, 0};
  if (mg < C2) {
    const float* src = W + (size_t)mg * K_DIM + k;
    f32x4 a = *(const f32x4*)src, b = *(const f32x4*)(src + 4);
    v[0] = (short)f2bf(a[0]); v[1] = (short)f2bf(a[1]);
    v[2] = (short)f2bf(a[2]); v[3] = (short)f2bf(a[3]);
    v[4] = (short)f2bf(b[0]); v[5] = (short)f2bf(b[1]);
    v[6] = (short)f2bf(b[2]); v[7] = (short)f2bf(b[3]);
  }
  *(bf16x8*)&Wswz[(size_t)g * 8] = v;
}

// ---------------- Stage 1: bf16 MFMA K-split GEMM --------------------------
// R8 skeleton; W-path replaced by global_load_lds from pre-swizzled Wswz:
// no W register loads, no W converts, no W ds_writes in the hot loop.
// A-path byte-identical to R8 (depth-2 reg prefetch, convert, swizzled write).
__global__ __launch_bounds__(512, 2) void k_gemm(
    const unsigned short* __restrict__ Wswz, const float* __restrict__ Am,
    unsigned short* __restrict__ part)
{
  __shared__ __align__(16) unsigned short sW[2 * BM * BK];  // 32 KB dbuf
  __shared__ __align__(16) unsigned short sA[2 * BN * BK];  // 32 KB dbuf

  const int t    = threadIdx.x;
  const int lane = t & 63;
  const int bid  = blockIdx.x;

  // XCD-chunked remap (bijective, 256 % 8 == 0): XCD owns 2 kc x all tiles.
  const int wk    = (bid & 7) * 32 + (bid >> 3);
  const int nt8   = wk & 7;
  const int mtile = (wk >> 3) & 1;
  const int kc    = wk >> 4;            // 0..15

  const int wid = t >> 6;
  const int mg  = wid >> 2;       // 2 groups of 64 m
  const int ng  = wid & 3;        // 4 groups of 32 n
  const int l15 = lane & 15;
  const int lk8 = (lane >> 4) * 8;

  const int n0b = nt8 * BN;
  const int m0b = mtile * BM;
  const int k0  = kc * KCHUNK;

  // W source: 8 slabs (one per step) of 1024 chunks, linear.
  const unsigned short* wsrc =
      Wswz + (size_t)((mtile * 16 + kc) * 8) * 8192;  // shorts
  const int wofs = (wid * 2) * 512;  // wave's 2x1024B segments (in shorts)

  // A staging: thread -> (2 cols at 2*(t&63), 8 k at wid*8); 8 f32x2 loads.
  const int san = (t & 63) * 2;
  const int sak = (t >> 6) * 8;
  const float* ap = Am + (size_t)(k0 + sak) * L_DIM + n0b + san;

  f32x2 aregs[2][8];
  f32x4 acc[4][2];
#pragma unroll
  for (int i = 0; i < 4; ++i)
#pragma unroll
    for (int j = 0; j < 2; ++j) acc[i][j] = (f32x4){0.f, 0.f, 0.f, 0.f};

  // prologue: W step-0 via gload_lds into buf0; A steps 0,1 into regs.
  {
    unsigned short* dst = sW + wofs;
    const unsigned short* src = wsrc + wofs + lane * 8;
    gload16(src, dst);
    gload16(src + 512, dst + 512);
  }
#pragma unroll
  for (int p = 0; p < 2; ++p)
#pragma unroll
    for (int r = 0; r < 8; ++r)
      aregs[p][r] = *(const f32x2*)(ap + (size_t)(p * BK + r) * L_DIM);

#pragma unroll
  for (int s = 0; s < NSTEP; ++s) {
    unsigned short* swb = sW + (s & 1) * (BM * BK);
    unsigned short* sab = sA + (s & 1) * (BN * BK);

    // ---- A: convert + swizzled LDS write from reg set s&1 ----
#pragma unroll
    for (int j = 0; j < 2; ++j) {       // two cols, 8 k each
      const int n = san + j;
      bf16x8 v;
#pragma unroll
      for (int r = 0; r < 8; ++r)
        v[r] = (short)f2bf(j ? aregs[s & 1][r][1] : aregs[s & 1][r][0]);
      *(bf16x8*)&sab[n * BK + (sak ^ ((n & 7) << 3))] = v;
    }

    __syncthreads();  // full drain: W gload_lds for step s has landed

    // ---- prefetch: W(s+1) via gload_lds into the freed buffer ----
    // Safe: buf (s+1)&1 was last read at step s-1; all waves passed the
    // barrier above, so those reads are complete.
    if (s + 1 < NSTEP) {
      unsigned short* dst = sW + ((s + 1) & 1) * (BM * BK) + wofs;
      const unsigned short* src = wsrc + (size_t)(s + 1) * 8192 + wofs + lane * 8;
      gload16(src, dst);
      gload16(src + 512, dst + 512);
    }
    // ---- prefetch: A(s+2) into reg set s&1 (depth-2, as R8) ----
    if (s + 2 < NSTEP) {
      const float* ap2 = ap + (size_t)(s + 2) * BK * L_DIM;
#pragma unroll
      for (int r = 0; r < 8; ++r)
        aregs[s & 1][r] = *(const f32x2*)(ap2 + (size_t)r * L_DIM);
    }

    // ---- compute from LDS buffer s&1 ----
#pragma unroll
    for (int kk = 0; kk < BK; kk += 32) {
      bf16x8 wf[4], af[2];
#pragma unroll
      for (int mt = 0; mt < 4; ++mt) {
        int m = mg * 64 + mt * 16 + l15;
        wf[mt] = *(const bf16x8*)&swb[m * BK + ((kk + lk8) ^ ((m & 7) << 3))];
      }
#pragma unroll
      for (int nt = 0; nt < 2; ++nt) {
        int n = ng * 32 + nt * 16 + l15;
        af[nt] = *(const bf16x8*)&sab[n * BK + ((kk + lk8) ^ ((n & 7) << 3))];
      }
#pragma unroll
      for (int mt = 0; mt < 4; ++mt)
#pragma unroll
        for (int nt = 0; nt < 2; ++nt)
          acc[mt][nt] = __builtin_amdgcn_mfma_f32_16x16x32_bf16(
              wf[mt], af[nt], acc[mt][nt], 0, 0, 0);
    }
    // single barrier/step: next iteration writes the other LDS buffer
  }

  // ---- store transposed bf16 partials: part[kc][n][m] ----
  unsigned short* pb = part + (size_t)kc * PART_KC;
#pragma unroll
  for (int mt = 0; mt < 4; ++mt) {
    const int m0 = m0b + mg * 64 + mt * 16 + (lane >> 4) * 4;
#pragma unroll
    for (int nt = 0; nt < 2; ++nt) {
      const int n = n0b + ng * 32 + nt * 16 + l15;
      bf16x4 v;
      v[0] = (short)f2bf(acc[mt][nt][0]);
      v[1] = (short)f2bf(acc[mt][nt][1]);
      v[2] = (short)f2bf(acc[mt][nt][2]);
      v[3] = (short)f2bf(acc[mt][nt][3]);
      *(bf16x4*)&pb[(size_t)n * MSTRIDE + m0] = v;
    }
  }
}

// ---------------- Stage 2: kc-reduce + bias + ReLU + m-reductions ----------
__global__ __launch_bounds__(256) void k_colbuf(
    const unsigned short* __restrict__ part, const float* __restrict__ b3,
    const float* __restrict__ w4, const float* __restrict__ b4,
    float* __restrict__ colbuf)
{
  __shared__ float red[2][4];
  const int n = blockIdx.x;
  const int t = threadIdx.x;
  const unsigned short* p = part + (size_t)n * MSTRIDE + t;
  float s = 0.f;
#pragma unroll
  for (int kcc = 0; kcc < KSPLIT; ++kcc)
    s += bf2f(p[(size_t)kcc * PART_KC]);
  float e = 0.f, c4 = 0.f;
  if (t < C2) {
    e  = fmaxf(s + b3[t], 0.f);
    c4 = w4[t] * e;
  }
#pragma unroll
  for (int off = 32; off; off >>= 1) {
    e  += __shfl_xor(e, off);
    c4 += __shfl_xor(c4, off);
  }
  const int wv = t >> 6;
  if ((t & 63) == 0) { red[0][wv] = e; red[1][wv] = c4; }
  __syncthreads();
  if (t == 0) {
    const float cs  = red[0][0] + red[0][1] + red[0][2] + red[0][3];
    const float tc4 = red[1][0] + red[1][1] + red[1][2] + red[1][3] + b4[0];
    const float mask = 1.f / (1.f + expf(-tc4));
    colbuf[n] = cs * (1.f + mask) * (1.f / (float)L_DIM);
  }
}

// ---------------- Stage 3: broadcast to all nodes (R8 form, proven) --------
__global__ __launch_bounds__(256) void k_broadcast(
    const float* __restrict__ colbuf, float4* __restrict__ out)
{
  const size_t idx = (size_t)blockIdx.x * 256 + threadIdx.x;  // float4 index
  const int nq = (int)(idx & 255);
  const float4 v = *(const float4*)(colbuf + nq * 4);
  out[idx] = v;
}

extern "C" void kernel_launch(void* const* d_in, const int* in_sizes, int n_in,
                              void* d_out, int out_size, void* d_ws, size_t ws_size,
                              hipStream_t stream) {
  // inputs: x, edge_index, edge_attr, conv3_w, conv3_b, conv4_w, conv4_b
  const float* edge_attr = (const float*)d_in[2];   // [8192][1024]
  const float* w3        = (const float*)d_in[3];   // [240][8192]
  const float* b3        = (const float*)d_in[4];   // [240]
  const float* w4        = (const float*)d_in[5];   // [240]
  const float* b4        = (const float*)d_in[6];   // [1]

  float* out = (float*)d_out;

  // ws layout (measured ws ~268MB): part 8.4MB | colbuf 4KB | Wswz 4MB.
  unsigned short* part;
  float* colbuf;
  unsigned short* wswz;
  if (ws_size >= PART_BYTES + 4096 + WSWZ_BYTES) {
    part   = (unsigned short*)d_ws;
    colbuf = (float*)((char*)d_ws + PART_BYTES);
    wswz   = (unsigned short*)((char*)d_ws + PART_BYTES + 4096);
  } else {
    // fallback: scratch inside d_out (fully overwritten by broadcast)
    part   = (unsigned short*)d_out;                       // 8.4 MB @ 0
    wswz   = (unsigned short*)((char*)d_out + 25165824);   // 4 MB @ 24MB
    colbuf = (float*)d_ws;
  }

  k_wconv     <<<dim3(1024),  256, 0, stream>>>(w3, wswz);
  k_gemm      <<<dim3(256),   512, 0, stream>>>(wswz, edge_attr, part);
  k_colbuf    <<<dim3(1024),  256, 0, stream>>>(part, b3, w4, b4, colbuf);
  k_broadcast <<<dim3(10000), 256, 0, stream>>>(colbuf, (float4*)out);
}